// Round 17
// baseline (293.451 us; speedup 1.0000x reference)
//
#include <hip/hip_runtime.h>
#include <hip/hip_bf16.h>
#include <hip/hip_fp16.h>
#include <math.h>

#define NF 256
#define NH 64
#define NC 16
#define NBMAX 512      // max buckets (N/256 <= 512 -> N <= 131072)
#define BTILE 4096     // edges per bin block
#define PCAP 6144      // LDS staging capacity in k_prep (bucket edges ~4096+-64)

typedef __attribute__((ext_vector_type(8))) __bf16 bf16x8;
typedef __attribute__((ext_vector_type(4))) float f32x4;
typedef __attribute__((ext_vector_type(2))) float f32x2;
typedef __attribute__((ext_vector_type(8))) short short8;

__device__ __forceinline__ unsigned short f2bf(float v) {   // RNE fp32->bf16
    unsigned u = __float_as_uint(v);
    unsigned r = u + 0x7fffu + ((u >> 16) & 1u);
    return (unsigned short)(r >> 16);
}
__device__ __forceinline__ float bf2f(unsigned short s) {
    return __uint_as_float(((unsigned)s) << 16);
}

// ---------------- bucket cursor init: bcur[b] = b*cap ----------------
__global__ void k_binit(int* __restrict__ bcur, int NB, int cap) {
    int b = blockIdx.x * 256 + threadIdx.x;
    if (b < NB) bcur[b] = b * cap;
}

// ---------------- FUSED: edge binning (blocks < nBin) + gemm1 (rest) ----------
// Bin blocks FIRST (R12): their latency/atomic phase overlaps gemm compute.
// R17 GEMM: K-step widened 32->64, SINGLE 32KB buffer. Same loop shape as the
// proven R3/R12 staging (loads inside the staging block, 2 barriers/step) but
// 4 phases instead of 8 -- halves barrier drains, doubles loads in flight per
// phase. Distinct from R5's failure (dbuf+prefetch regs): VGPR stays 32; LDS
// 32KB -> 5 blocks/CU = 20 waves > the 17 currently achieved. MFMA k-order
// identical (sub-steps s=0,1 execute k0..31 then k0+32..63) -> same absmax.
__global__ __launch_bounds__(256) void k_bingemm1(const float* __restrict__ x,
                                                  const float* __restrict__ W1,
                                                  __half* __restrict__ h1, int n,
                                                  const int* __restrict__ src,
                                                  const int* __restrict__ dst,
                                                  int* __restrict__ bcur,
                                                  int* __restrict__ binned,
                                                  int E, int NB, int nBin) {
    __shared__ __align__(16) unsigned char smem[32768];
    int tid = threadIdx.x;
    if ((int)blockIdx.x >= nBin) {
        // ---- GEMM1 (MFMA bf16 hi/lo split): h1(fp16) = x @ W1 ----
        unsigned short* Ah = (unsigned short*)smem;   // [2 subtiles][2048]
        unsigned short* Al = Ah + 4096;
        unsigned short* Bh = Al + 4096;
        unsigned short* Bl = Bh + 4096;
        int lane = tid & 63;
        int wid = tid >> 6;          // rowgroup 0..3
        int m0 = ((int)blockIdx.x - nBin) * 64;
        f32x4 acc[4] = {{0.f, 0.f, 0.f, 0.f}, {0.f, 0.f, 0.f, 0.f},
                        {0.f, 0.f, 0.f, 0.f}, {0.f, 0.f, 0.f, 0.f}};
        int bcol = tid & 63;
        int bkq = tid >> 6;          // k-quad 0..3
        int bIdx = ((bcol >> 4) * 512) + (((bkq << 4) | (bcol & 15)) * 8);  // shorts

        for (int k0 = 0; k0 < NF; k0 += 64) {
            // A-stage: 64 rows x 64 cols fp32 -> bf16 hi/lo, 4 chunks/thread
            #pragma unroll
            for (int it = 0; it < 4; ++it) {
                int f = tid + it * 256;   // 0..1023
                int m = f >> 4;           // row 0..63
                int gg = f & 15;          // col-block of 4 within 64
                int s = gg >> 3;          // K=32 sub-tile
                int g = gg & 7;
                int node = m0 + m;
                float4 xv = make_float4(0.f, 0.f, 0.f, 0.f);
                if (node < n) xv = *(const float4*)&x[(size_t)node * NF + k0 + s * 32 + g * 4];
                ushort4 hi, lo;
                hi.x = f2bf(xv.x); lo.x = f2bf(xv.x - bf2f(hi.x));
                hi.y = f2bf(xv.y); lo.y = f2bf(xv.y - bf2f(hi.y));
                hi.z = f2bf(xv.z); lo.z = f2bf(xv.z - bf2f(hi.z));
                hi.w = f2bf(xv.w); lo.w = f2bf(xv.w - bf2f(hi.w));
                int aIdx = s * 2048 + ((m >> 4) * 512) +
                           ((((g >> 1) << 4) | (m & 15)) * 8) + (g & 1) * 4;
                *(ushort4*)&Ah[aIdx] = hi;
                *(ushort4*)&Al[aIdx] = lo;
            }
            // B-stage: two K=32 sub-tiles, 16 scalar W1 loads/thread
            #pragma unroll
            for (int s = 0; s < 2; ++s) {
                unsigned short hb[8], lb[8];
                #pragma unroll
                for (int j = 0; j < 8; ++j) {
                    float w = W1[(size_t)(k0 + s * 32 + bkq * 8 + j) * NH + bcol];
                    hb[j] = f2bf(w);
                    lb[j] = f2bf(w - bf2f(hb[j]));
                }
                #pragma unroll
                for (int j = 0; j < 8; ++j) {
                    Bh[s * 2048 + bIdx + j] = hb[j];
                    Bl[s * 2048 + bIdx + j] = lb[j];
                }
            }
            __syncthreads();
            #pragma unroll
            for (int s = 0; s < 2; ++s) {
                bf16x8 ah = __builtin_bit_cast(bf16x8,
                    *(short8*)&Ah[s * 2048 + wid * 512 + lane * 8]);
                bf16x8 al = __builtin_bit_cast(bf16x8,
                    *(short8*)&Al[s * 2048 + wid * 512 + lane * 8]);
                #pragma unroll
                for (int c = 0; c < 4; ++c) {
                    bf16x8 bh = __builtin_bit_cast(bf16x8,
                        *(short8*)&Bh[s * 2048 + c * 512 + lane * 8]);
                    bf16x8 bl = __builtin_bit_cast(bf16x8,
                        *(short8*)&Bl[s * 2048 + c * 512 + lane * 8]);
                    acc[c] = __builtin_amdgcn_mfma_f32_16x16x32_bf16(ah, bh, acc[c], 0, 0, 0);
                    acc[c] = __builtin_amdgcn_mfma_f32_16x16x32_bf16(al, bh, acc[c], 0, 0, 0);
                    acc[c] = __builtin_amdgcn_mfma_f32_16x16x32_bf16(ah, bl, acc[c], 0, 0, 0);
                }
            }
            __syncthreads();
        }
        int quad = lane >> 4;
        int cl = lane & 15;
        #pragma unroll
        for (int c = 0; c < 4; ++c) {
            #pragma unroll
            for (int r = 0; r < 4; ++r) {
                int row = m0 + wid * 16 + quad * 4 + r;
                if (row < n) h1[(size_t)row * NH + c * 16 + cl] = __float2half_rn(acc[c][r]);
            }
        }
    } else {
        // ---- edge binning by dst>>8; packed entry: src | (dst&255)<<24 ----
        int* histA = (int*)smem;
        int* histB = histA + NBMAX;
        int* gbase = histB + NBMAX;
        int e0 = (int)blockIdx.x * BTILE;
        for (int b = tid; b < NB; b += 256) { histA[b] = 0; histB[b] = 0; }
        __syncthreads();
        #pragma unroll
        for (int u = 0; u < BTILE / 256; ++u) {
            int i = e0 + u * 256 + tid;
            if (i < E) atomicAdd(&histA[dst[i] >> 8], 1);
        }
        __syncthreads();
        for (int b = tid; b < NB; b += 256) {
            int c = histA[b];
            gbase[b] = c ? atomicAdd(&bcur[b], c) : 0;
        }
        __syncthreads();
        #pragma unroll
        for (int u = 0; u < BTILE / 256; ++u) {
            int i = e0 + u * 256 + tid;
            if (i < E) {
                int d = dst[i];
                int b = d >> 8;
                int r = atomicAdd(&histB[b], 1);
                binned[gbase[b] + r] = src[i] | ((d & 255) << 24);
            }
        }
    }
}

// ---------------- prep: bucket base + hist + scan + scatter + H1 PRE-SCALE -----
// Factorized normalization (R11): agg[v] = dinv_v*(sum h'[s] + h'[v]) with
// h' = dinv*h1; prep scales h1 in place (coalesced 8-pass over its 256 nodes).
__global__ __launch_bounds__(256) void k_prep(const int* __restrict__ binned,
                                              const int* __restrict__ bcur,
                                              int2* __restrict__ rowcnt,
                                              float* __restrict__ dinv,
                                              int* __restrict__ esrc,
                                              __half* __restrict__ h1,
                                              int cap, int N, int NB) {
    __shared__ int eb[PCAP];
    __shared__ int h[256], sc[256], red[256];
    __shared__ float dvs[256];
    int b = blockIdx.x;
    int tid = threadIdx.x;
    int node0 = b << 8;
    int base = b * cap;
    int ne = bcur[b] - base;
    if (ne > PCAP) ne = PCAP;   // safety (never hit at this E/N)
    for (int i = tid; i < ne; i += 256) eb[i] = binned[base + i];
    // partial sums of preceding bucket sizes -> this bucket's global edge base
    int acc = 0;
    for (int i = tid; i < b; i += 256) acc += bcur[i] - i * cap;
    h[tid] = 0;
    red[tid] = acc;
    __syncthreads();
    for (int i = tid; i < ne; i += 256) atomicAdd(&h[(eb[i] >> 24) & 255], 1);
    __syncthreads();
    for (int off = 128; off > 0; off >>= 1) {
        if (tid < off) red[tid] += red[tid + off];
        __syncthreads();
    }
    int bbase_b = red[0];
    int c = h[tid];
    sc[tid] = c;
    __syncthreads();
    for (int off = 1; off < 256; off <<= 1) {
        int add = (tid >= off) ? sc[tid - off] : 0;
        __syncthreads();
        sc[tid] += add;
        __syncthreads();
    }
    int rp = bbase_b + sc[tid] - c;       // exclusive, bucket-major
    int v = node0 + tid;
    float dvf = rsqrtf((float)(c + 1));
    dvs[tid] = dvf;
    if (v < N) {
        rowcnt[v] = make_int2(rp, c);
        dinv[v] = dvf;
    }
    sc[tid] = rp;                         // reuse as scatter cursor
    __syncthreads();
    for (int i = tid; i < ne; i += 256) {
        int pk = eb[i];
        int pos = atomicAdd(&sc[(pk >> 24) & 255], 1);
        esrc[pos] = pk & 0x00FFFFFF;
    }
    __syncthreads();
    // in-place h1 scale: 8 passes x 32 rows, 8 threads/row, 16B/lane coalesced
    #pragma unroll
    for (int pass = 0; pass < 8; ++pass) {
        int r = (tid >> 3) + pass * 32;
        int vv = node0 + r;
        if (vv < N) {
            float dv = dvs[r];
            __half* prow = &h1[(size_t)vv * NH + (tid & 7) * 8];
            uint4 pk = *(uint4*)prow;
            __half2* ph = (__half2*)&pk;
            #pragma unroll
            for (int q = 0; q < 4; ++q) {
                float2 f = __half22float2(ph[q]);
                ph[q] = __floats2half2_rn(dv * f.x, dv * f.y);
            }
            *(uint4*)prow = pk;
        }
    }
}

// ---------------- agg1 + bias + relu + FUSED GEMM2 -> g'(fp16), DUAL-NODE ------
// Weightless gathers: h1 is pre-scaled (h'). Per node: S = sum h'[s] (+h'[v]
// self on slot 0), then a = dv*S + b1, relu, gemm2, store g' = dv*gout.
// 32-edge batches -> 8 independent h' row gathers in flight; masks 1/0 via
// pk_fma. Grid-stride 2048 blocks (R4 lesson). es = lane>>3, fl = lane&7.
__global__ __launch_bounds__(256) void k_agg1f(const __half* __restrict__ h1,
                                               const float* __restrict__ dinv,
                                               const int2* __restrict__ rowcnt,
                                               const int* __restrict__ esrc,
                                               const float* __restrict__ b1,
                                               const float* __restrict__ W2,
                                               __half2* __restrict__ g, int n) {
    int lane = threadIdx.x & 63;
    int wid = threadIdx.x >> 6;
    int es = lane >> 3;
    int fl = lane & 7;
    float2 w2[8];
    float b1r[8];
    #pragma unroll
    for (int k = 0; k < 8; ++k) {
        w2[k] = *(const float2*)&W2[(size_t)(8 * fl + k) * NC + 2 * es];
        b1r[k] = b1[8 * fl + k];
    }
    int pairs = (n + 1) >> 1;
    int stride = gridDim.x * 4;
    for (int p = blockIdx.x * 4 + wid; p < pairs; p += stride) {
        int v0 = 2 * p;
        int v1 = v0 + 1;
        bool val1 = v1 < n;
        int beg0, c0, beg1, c1;
        float dv0, dv1;
        if (val1) {
            int4 rc = *(const int4*)&rowcnt[v0];     // v0 even -> 16B aligned
            beg0 = rc.x; c0 = rc.y; beg1 = rc.z; c1 = rc.w;
            float2 dd = *(const float2*)&dinv[v0];
            dv0 = dd.x; dv1 = dd.y;
        } else {
            int2 rc = rowcnt[v0];
            beg0 = rc.x; c0 = rc.y; beg1 = 0; c1 = 0;
            dv0 = dinv[v0]; dv1 = 0.f;
        }
        // prefetch first 32-edge batch for both nodes (broadcast int loads)
        int sA[4], sB[4];
        #pragma unroll
        for (int k = 0; k < 4; ++k) {
            int i = es + 8 * k;
            sA[k] = esrc[i < c0 ? beg0 + i : 0];
            sB[k] = esrc[i < c1 ? beg1 + i : 0];
        }
        f32x2 a0v[4], a1v[4];
        #pragma unroll
        for (int q = 0; q < 4; ++q) { a0v[q] = (f32x2){0.f, 0.f}; a1v[q] = (f32x2){0.f, 0.f}; }
        {   // self terms h'[v] (weight 1 on slot es==0 only)
            float sw0 = (es == 0) ? 1.f : 0.f;
            float sw1 = (es == 0 && val1) ? 1.f : 0.f;
            uint4 q0 = *(const uint4*)&h1[(size_t)v0 * NH + 8 * fl];
            uint4 q1 = *(const uint4*)&h1[(size_t)(val1 ? v1 : v0) * NH + 8 * fl];
            const __half2* ph0 = (const __half2*)&q0;
            const __half2* ph1 = (const __half2*)&q1;
            #pragma unroll
            for (int q = 0; q < 4; ++q) {
                float2 f0 = __half22float2(ph0[q]);
                float2 f1 = __half22float2(ph1[q]);
                a0v[q] += sw0 * (f32x2){f0.x, f0.y};
                a1v[q] += sw1 * (f32x2){f1.x, f1.y};
            }
        }
        int cmax = c0 > c1 ? c0 : c1;
        for (int base = 0; base < cmax; base += 32) {
            int cA[4], cB[4];
            #pragma unroll
            for (int k = 0; k < 4; ++k) { cA[k] = sA[k]; cB[k] = sB[k]; }
            int nb = base + 32;
            if (nb < cmax) {   // prefetch next batch
                #pragma unroll
                for (int k = 0; k < 4; ++k) {
                    int j = nb + es + 8 * k;
                    sA[k] = esrc[j < c0 ? beg0 + j : 0];
                    sB[k] = esrc[j < c1 ? beg1 + j : 0];
                }
            }
            // validity masks (1/0)
            float mA[4], mB[4];
            #pragma unroll
            for (int k = 0; k < 4; ++k) {
                int e = base + es + 8 * k;
                mA[k] = (e < c0) ? 1.f : 0.f;
                mB[k] = (e < c1) ? 1.f : 0.f;
            }
            // 8 independent h' row-slice gathers (16B each)
            uint4 pA[4], pB[4];
            #pragma unroll
            for (int k = 0; k < 4; ++k) {
                pA[k] = *(const uint4*)&h1[(size_t)cA[k] * NH + 8 * fl];
                pB[k] = *(const uint4*)&h1[(size_t)cB[k] * NH + 8 * fl];
            }
            #pragma unroll
            for (int k = 0; k < 4; ++k) {
                const __half2* qA = (const __half2*)&pA[k];
                const __half2* qB = (const __half2*)&pB[k];
                #pragma unroll
                for (int q = 0; q < 4; ++q) {
                    float2 fA = __half22float2(qA[q]);
                    float2 fB = __half22float2(qB[q]);
                    a0v[q] += mA[k] * (f32x2){fA.x, fA.y};
                    a1v[q] += mB[k] * (f32x2){fB.x, fB.y};
                }
            }
        }
        // unpack, reduce across the 8 edge-slots (xor 8,16,32)
        float a0[8], a1[8];
        #pragma unroll
        for (int q = 0; q < 4; ++q) {
            a0[2 * q] = a0v[q][0]; a0[2 * q + 1] = a0v[q][1];
            a1[2 * q] = a1v[q][0]; a1[2 * q + 1] = a1v[q][1];
        }
        #pragma unroll
        for (int m = 8; m < 64; m <<= 1) {
            #pragma unroll
            for (int k = 0; k < 8; ++k) {
                a0[k] += __shfl_xor(a0[k], m);
                a1[k] += __shfl_xor(a1[k], m);
            }
        }
        // a = dv*S + b1, relu, fused GEMM2 partials
        float p00 = 0.f, p01 = 0.f, p10 = 0.f, p11 = 0.f;
        #pragma unroll
        for (int k = 0; k < 8; ++k) {
            float h0 = fmaxf(fmaf(dv0, a0[k], b1r[k]), 0.f);
            float h1v = fmaxf(fmaf(dv1, a1[k], b1r[k]), 0.f);
            p00 = fmaf(h0, w2[k].x, p00);
            p01 = fmaf(h0, w2[k].y, p01);
            p10 = fmaf(h1v, w2[k].x, p10);
            p11 = fmaf(h1v, w2[k].y, p11);
        }
        #pragma unroll
        for (int m = 1; m < 8; m <<= 1) {   // reduce over fl (xor 1,2,4)
            p00 += __shfl_xor(p00, m);
            p01 += __shfl_xor(p01, m);
            p10 += __shfl_xor(p10, m);
            p11 += __shfl_xor(p11, m);
        }
        if (fl == 0) {   // store g' = dv * gout
            g[(size_t)v0 * 8 + es] = __floats2half2_rn(dv0 * p00, dv0 * p01);
            if (val1) g[(size_t)v1 * 8 + es] = __floats2half2_rn(dv1 * p10, dv1 * p11);
        }
    }
}

// ---------------- agg2 + bias + log_softmax: 8-lane group/node, weightless -----
// g' table fp16 (3.2 MB, L2-resident). out_pre = dv*(g'[v] + sum g'[s]) + b2.
// 16-edge two-phase batches of masked adds; lane cl owns class pair (2cl,2cl+1).
__global__ __launch_bounds__(256) void k_agg2v(const __half2* __restrict__ g,
                                               const float* __restrict__ dinv,
                                               const int2* __restrict__ rowcnt,
                                               const int* __restrict__ esrc,
                                               const float* __restrict__ b2,
                                               float* __restrict__ out, int n) {
    int v = blockIdx.x * 32 + (threadIdx.x >> 3);
    int cl = threadIdx.x & 7;
    if (v >= n) return;
    float dv = dinv[v];
    int2 rc = rowcnt[v];
    f32x2 av;
    {   // self term g'[v], weight 1
        float2 f = __half22float2(g[(size_t)v * 8 + cl]);
        av = (f32x2){f.x, f.y};
    }
    int beg = rc.x, cnt = rc.y;
    for (int base = 0; base < cnt; base += 16) {
        int e[16];
        #pragma unroll
        for (int u = 0; u < 16; ++u) {
            int ei = base + u;
            e[u] = esrc[ei < cnt ? beg + ei : 0];
        }
        #pragma unroll
        for (int u = 0; u < 16; ++u) {
            float m = (base + u < cnt) ? 1.f : 0.f;
            float2 f = __half22float2(g[(size_t)e[u] * 8 + cl]);
            av += m * (f32x2){f.x, f.y};
        }
    }
    float ax = fmaf(dv, av[0], b2[2 * cl]);
    float ay = fmaf(dv, av[1], b2[2 * cl + 1]);
    float m = fmaxf(ax, ay);
    #pragma unroll
    for (int mask = 1; mask < 8; mask <<= 1) m = fmaxf(m, __shfl_xor(m, mask, 8));
    float ex = __expf(ax - m) + __expf(ay - m);
    #pragma unroll
    for (int mask = 1; mask < 8; mask <<= 1) ex += __shfl_xor(ex, mask, 8);
    float ls = m + __logf(ex);
    *(float2*)&out[(size_t)v * NC + 2 * cl] = make_float2(ax - ls, ay - ls);
}

extern "C" void kernel_launch(void* const* d_in, const int* in_sizes, int n_in,
                              void* d_out, int out_size, void* d_ws, size_t ws_size,
                              hipStream_t stream) {
    const float* x  = (const float*)d_in[0];
    const int*   ei = (const int*)d_in[1];
    const float* W1 = (const float*)d_in[2];
    const float* b1 = (const float*)d_in[3];
    const float* W2 = (const float*)d_in[4];
    const float* b2 = (const float*)d_in[5];
    float* out = (float*)d_out;

    const int N = in_sizes[0] / NF;
    const int E = in_sizes[1] / 2;
    const int* src = ei;
    const int* dst = ei + E;

    const int NB  = (N + 255) >> 8;                       // buckets of 256 nodes
    const int per = (E + NB - 1) / NB;
    const int cap = (per + (per >> 2) + 511) & ~511;      // +25% slack, 512-aligned

    // workspace layout (64B-aligned slices; no aliasing)
    char* ws = (char*)d_ws;
    size_t o = 0;
    auto alloc = [&](size_t bytes) {
        o = (o + 63) & ~(size_t)63;
        void* p = ws + o;
        o += bytes;
        return p;
    };
    int2*   rowcnt = (int2*)alloc((size_t)N * 8);
    float*  dinv   = (float*)alloc((size_t)N * 4);
    int*    bcur   = (int*)alloc((size_t)NBMAX * 4);
    int*    esrc   = (int*)alloc((size_t)E * 4);            // 6.4 MB
    __half* h1     = (__half*)alloc((size_t)N * NH * 2);    // 12.8 MB fp16 (pre-scaled)
    __half2* g     = (__half2*)alloc((size_t)N * NC * 2);   // 3.2 MB fp16 (g' = dv*gout)
    int*    binned = (int*)alloc((size_t)NB * cap * 4);     // ~8 MB

    int nbin = (E + BTILE - 1) / BTILE;
    int nGemm = (N + 63) / 64;

    k_binit<<<(NB + 255) / 256, 256, 0, stream>>>(bcur, NB, cap);
    k_bingemm1<<<nbin + nGemm, 256, 0, stream>>>(x, W1, h1, N, src, dst, bcur, binned,
                                                 E, NB, nbin);
    k_prep<<<NB, 256, 0, stream>>>(binned, bcur, rowcnt, dinv, esrc, h1, cap, N, NB);
    k_agg1f<<<2048, 256, 0, stream>>>(h1, dinv, rowcnt, esrc, b1, W2, g, N);
    k_agg2v<<<(N + 31) / 32, 256, 0, stream>>>(g, dinv, rowcnt, esrc, b2, out, N);
}

// Round 18
// 288.363 us; speedup vs baseline: 1.0176x; 1.0176x over previous
//
#include <hip/hip_runtime.h>
#include <hip/hip_bf16.h>
#include <hip/hip_fp16.h>
#include <math.h>

#define NF 256
#define NH 64
#define NC 16
#define NBMAX 512      // max buckets (N/256 <= 512 -> N <= 131072)
#define BTILE 4096     // edges per bin block
#define PCAP 6144      // LDS staging capacity in k_prep (bucket edges ~4096+-64)

typedef __attribute__((ext_vector_type(8))) __bf16 bf16x8;
typedef __attribute__((ext_vector_type(4))) float f32x4;
typedef __attribute__((ext_vector_type(2))) float f32x2;
typedef __attribute__((ext_vector_type(8))) short short8;

__device__ __forceinline__ unsigned short f2bf(float v) {   // RNE fp32->bf16
    unsigned u = __float_as_uint(v);
    unsigned r = u + 0x7fffu + ((u >> 16) & 1u);
    return (unsigned short)(r >> 16);
}
__device__ __forceinline__ float bf2f(unsigned short s) {
    return __uint_as_float(((unsigned)s) << 16);
}

// ---------------- bucket cursor init: bcur[b] = b*cap ----------------
__global__ void k_binit(int* __restrict__ bcur, int NB, int cap) {
    int b = blockIdx.x * 256 + threadIdx.x;
    if (b < NB) bcur[b] = b * cap;
}

// ---------------- FUSED: edge binning (blocks < nBin) + gemm1 (rest) ----------
// R12 configuration == measured best (288.0us total, fused ~74us).
// Bin blocks FIRST: their latency/atomic phase overlaps gemm compute filling
// in behind; kernel tail is dense MFMA work.
// GEMM path: EXACT R3 loop -- 16KB single-buffer LDS staging, loads issued
// inside the staging loop, 2 barriers/K-step. Eight rewrites (dbuf, LDS-free,
// reg-array, prefetch, async-DMA, global-B x2, K=64) all landed 74-93us:
// this shape is the local optimum. Final.
__global__ __launch_bounds__(256) void k_bingemm1(const float* __restrict__ x,
                                                  const float* __restrict__ W1,
                                                  __half* __restrict__ h1, int n,
                                                  const int* __restrict__ src,
                                                  const int* __restrict__ dst,
                                                  int* __restrict__ bcur,
                                                  int* __restrict__ binned,
                                                  int E, int NB, int nBin) {
    __shared__ __align__(16) unsigned char smem[16384];
    int tid = threadIdx.x;
    if ((int)blockIdx.x >= nBin) {
        // ---- GEMM1 (MFMA bf16 hi/lo split): h1(fp16) = x @ W1 ----
        unsigned short* Ah = (unsigned short*)smem;
        unsigned short* Al = Ah + 2048;
        unsigned short* Bh = Al + 2048;
        unsigned short* Bl = Bh + 2048;
        int lane = tid & 63;
        int wid = tid >> 6;          // rowgroup 0..3
        int m0 = ((int)blockIdx.x - nBin) * 64;
        f32x4 acc[4] = {{0.f, 0.f, 0.f, 0.f}, {0.f, 0.f, 0.f, 0.f},
                        {0.f, 0.f, 0.f, 0.f}, {0.f, 0.f, 0.f, 0.f}};
        int bcol = tid & 63;
        int bkq = tid >> 6;          // k-quad 0..3
        int bIdx = ((bcol >> 4) * 512) + (((bkq << 4) | (bcol & 15)) * 8);  // shorts

        for (int k0 = 0; k0 < NF; k0 += 32) {
            #pragma unroll
            for (int it = 0; it < 2; ++it) {
                int f = tid + it * 256;
                int m = f >> 3;
                int g = f & 7;
                int node = m0 + m;
                float4 xv = make_float4(0.f, 0.f, 0.f, 0.f);
                if (node < n) xv = *(const float4*)&x[(size_t)node * NF + k0 + g * 4];
                ushort4 hi, lo;
                hi.x = f2bf(xv.x); lo.x = f2bf(xv.x - bf2f(hi.x));
                hi.y = f2bf(xv.y); lo.y = f2bf(xv.y - bf2f(hi.y));
                hi.z = f2bf(xv.z); lo.z = f2bf(xv.z - bf2f(hi.z));
                hi.w = f2bf(xv.w); lo.w = f2bf(xv.w - bf2f(hi.w));
                int aIdx = ((m >> 4) * 512) + ((((g >> 1) << 4) | (m & 15)) * 8) + (g & 1) * 4;
                *(ushort4*)&Ah[aIdx] = hi;
                *(ushort4*)&Al[aIdx] = lo;
            }
            {
                unsigned short hb[8], lb[8];
                #pragma unroll
                for (int j = 0; j < 8; ++j) {
                    float w = W1[(size_t)(k0 + bkq * 8 + j) * NH + bcol];
                    hb[j] = f2bf(w);
                    lb[j] = f2bf(w - bf2f(hb[j]));
                }
                #pragma unroll
                for (int j = 0; j < 8; ++j) { Bh[bIdx + j] = hb[j]; Bl[bIdx + j] = lb[j]; }
            }
            __syncthreads();
            bf16x8 ah = __builtin_bit_cast(bf16x8, *(short8*)&Ah[wid * 512 + lane * 8]);
            bf16x8 al = __builtin_bit_cast(bf16x8, *(short8*)&Al[wid * 512 + lane * 8]);
            #pragma unroll
            for (int c = 0; c < 4; ++c) {
                bf16x8 bh = __builtin_bit_cast(bf16x8, *(short8*)&Bh[c * 512 + lane * 8]);
                bf16x8 bl = __builtin_bit_cast(bf16x8, *(short8*)&Bl[c * 512 + lane * 8]);
                acc[c] = __builtin_amdgcn_mfma_f32_16x16x32_bf16(ah, bh, acc[c], 0, 0, 0);
                acc[c] = __builtin_amdgcn_mfma_f32_16x16x32_bf16(al, bh, acc[c], 0, 0, 0);
                acc[c] = __builtin_amdgcn_mfma_f32_16x16x32_bf16(ah, bl, acc[c], 0, 0, 0);
            }
            __syncthreads();
        }
        int quad = lane >> 4;
        int cl = lane & 15;
        #pragma unroll
        for (int c = 0; c < 4; ++c) {
            #pragma unroll
            for (int r = 0; r < 4; ++r) {
                int row = m0 + wid * 16 + quad * 4 + r;
                if (row < n) h1[(size_t)row * NH + c * 16 + cl] = __float2half_rn(acc[c][r]);
            }
        }
    } else {
        // ---- edge binning by dst>>8; packed entry: src | (dst&255)<<24 ----
        int* histA = (int*)smem;
        int* histB = histA + NBMAX;
        int* gbase = histB + NBMAX;
        int e0 = (int)blockIdx.x * BTILE;
        for (int b = tid; b < NB; b += 256) { histA[b] = 0; histB[b] = 0; }
        __syncthreads();
        #pragma unroll
        for (int u = 0; u < BTILE / 256; ++u) {
            int i = e0 + u * 256 + tid;
            if (i < E) atomicAdd(&histA[dst[i] >> 8], 1);
        }
        __syncthreads();
        for (int b = tid; b < NB; b += 256) {
            int c = histA[b];
            gbase[b] = c ? atomicAdd(&bcur[b], c) : 0;
        }
        __syncthreads();
        #pragma unroll
        for (int u = 0; u < BTILE / 256; ++u) {
            int i = e0 + u * 256 + tid;
            if (i < E) {
                int d = dst[i];
                int b = d >> 8;
                int r = atomicAdd(&histB[b], 1);
                binned[gbase[b] + r] = src[i] | ((d & 255) << 24);
            }
        }
    }
}

// ---------------- prep: bucket base + hist + scan + scatter + H1 PRE-SCALE -----
// Factorized normalization (R11): agg[v] = dinv_v*(sum h'[s] + h'[v]) with
// h' = dinv*h1; prep scales h1 in place (coalesced 8-pass over its 256 nodes).
__global__ __launch_bounds__(256) void k_prep(const int* __restrict__ binned,
                                              const int* __restrict__ bcur,
                                              int2* __restrict__ rowcnt,
                                              float* __restrict__ dinv,
                                              int* __restrict__ esrc,
                                              __half* __restrict__ h1,
                                              int cap, int N, int NB) {
    __shared__ int eb[PCAP];
    __shared__ int h[256], sc[256], red[256];
    __shared__ float dvs[256];
    int b = blockIdx.x;
    int tid = threadIdx.x;
    int node0 = b << 8;
    int base = b * cap;
    int ne = bcur[b] - base;
    if (ne > PCAP) ne = PCAP;   // safety (never hit at this E/N)
    for (int i = tid; i < ne; i += 256) eb[i] = binned[base + i];
    // partial sums of preceding bucket sizes -> this bucket's global edge base
    int acc = 0;
    for (int i = tid; i < b; i += 256) acc += bcur[i] - i * cap;
    h[tid] = 0;
    red[tid] = acc;
    __syncthreads();
    for (int i = tid; i < ne; i += 256) atomicAdd(&h[(eb[i] >> 24) & 255], 1);
    __syncthreads();
    for (int off = 128; off > 0; off >>= 1) {
        if (tid < off) red[tid] += red[tid + off];
        __syncthreads();
    }
    int bbase_b = red[0];
    int c = h[tid];
    sc[tid] = c;
    __syncthreads();
    for (int off = 1; off < 256; off <<= 1) {
        int add = (tid >= off) ? sc[tid - off] : 0;
        __syncthreads();
        sc[tid] += add;
        __syncthreads();
    }
    int rp = bbase_b + sc[tid] - c;       // exclusive, bucket-major
    int v = node0 + tid;
    float dvf = rsqrtf((float)(c + 1));
    dvs[tid] = dvf;
    if (v < N) {
        rowcnt[v] = make_int2(rp, c);
        dinv[v] = dvf;
    }
    sc[tid] = rp;                         // reuse as scatter cursor
    __syncthreads();
    for (int i = tid; i < ne; i += 256) {
        int pk = eb[i];
        int pos = atomicAdd(&sc[(pk >> 24) & 255], 1);
        esrc[pos] = pk & 0x00FFFFFF;
    }
    __syncthreads();
    // in-place h1 scale: 8 passes x 32 rows, 8 threads/row, 16B/lane coalesced
    #pragma unroll
    for (int pass = 0; pass < 8; ++pass) {
        int r = (tid >> 3) + pass * 32;
        int vv = node0 + r;
        if (vv < N) {
            float dv = dvs[r];
            __half* prow = &h1[(size_t)vv * NH + (tid & 7) * 8];
            uint4 pk = *(uint4*)prow;
            __half2* ph = (__half2*)&pk;
            #pragma unroll
            for (int q = 0; q < 4; ++q) {
                float2 f = __half22float2(ph[q]);
                ph[q] = __floats2half2_rn(dv * f.x, dv * f.y);
            }
            *(uint4*)prow = pk;
        }
    }
}

// ---------------- agg1 + bias + relu + FUSED GEMM2 -> g'(fp16), DUAL-NODE ------
// Weightless gathers: h1 is pre-scaled (h'). Per node: S = sum h'[s] (+h'[v]
// self on slot 0), then a = dv*S + b1, relu, gemm2, store g' = dv*gout.
// 32-edge batches -> 8 independent h' row gathers in flight; masks 1/0 via
// pk_fma. Grid-stride 2048 blocks (R4 lesson). es = lane>>3, fl = lane&7.
__global__ __launch_bounds__(256) void k_agg1f(const __half* __restrict__ h1,
                                               const float* __restrict__ dinv,
                                               const int2* __restrict__ rowcnt,
                                               const int* __restrict__ esrc,
                                               const float* __restrict__ b1,
                                               const float* __restrict__ W2,
                                               __half2* __restrict__ g, int n) {
    int lane = threadIdx.x & 63;
    int wid = threadIdx.x >> 6;
    int es = lane >> 3;
    int fl = lane & 7;
    float2 w2[8];
    float b1r[8];
    #pragma unroll
    for (int k = 0; k < 8; ++k) {
        w2[k] = *(const float2*)&W2[(size_t)(8 * fl + k) * NC + 2 * es];
        b1r[k] = b1[8 * fl + k];
    }
    int pairs = (n + 1) >> 1;
    int stride = gridDim.x * 4;
    for (int p = blockIdx.x * 4 + wid; p < pairs; p += stride) {
        int v0 = 2 * p;
        int v1 = v0 + 1;
        bool val1 = v1 < n;
        int beg0, c0, beg1, c1;
        float dv0, dv1;
        if (val1) {
            int4 rc = *(const int4*)&rowcnt[v0];     // v0 even -> 16B aligned
            beg0 = rc.x; c0 = rc.y; beg1 = rc.z; c1 = rc.w;
            float2 dd = *(const float2*)&dinv[v0];
            dv0 = dd.x; dv1 = dd.y;
        } else {
            int2 rc = rowcnt[v0];
            beg0 = rc.x; c0 = rc.y; beg1 = 0; c1 = 0;
            dv0 = dinv[v0]; dv1 = 0.f;
        }
        // prefetch first 32-edge batch for both nodes (broadcast int loads)
        int sA[4], sB[4];
        #pragma unroll
        for (int k = 0; k < 4; ++k) {
            int i = es + 8 * k;
            sA[k] = esrc[i < c0 ? beg0 + i : 0];
            sB[k] = esrc[i < c1 ? beg1 + i : 0];
        }
        f32x2 a0v[4], a1v[4];
        #pragma unroll
        for (int q = 0; q < 4; ++q) { a0v[q] = (f32x2){0.f, 0.f}; a1v[q] = (f32x2){0.f, 0.f}; }
        {   // self terms h'[v] (weight 1 on slot es==0 only)
            float sw0 = (es == 0) ? 1.f : 0.f;
            float sw1 = (es == 0 && val1) ? 1.f : 0.f;
            uint4 q0 = *(const uint4*)&h1[(size_t)v0 * NH + 8 * fl];
            uint4 q1 = *(const uint4*)&h1[(size_t)(val1 ? v1 : v0) * NH + 8 * fl];
            const __half2* ph0 = (const __half2*)&q0;
            const __half2* ph1 = (const __half2*)&q1;
            #pragma unroll
            for (int q = 0; q < 4; ++q) {
                float2 f0 = __half22float2(ph0[q]);
                float2 f1 = __half22float2(ph1[q]);
                a0v[q] += sw0 * (f32x2){f0.x, f0.y};
                a1v[q] += sw1 * (f32x2){f1.x, f1.y};
            }
        }
        int cmax = c0 > c1 ? c0 : c1;
        for (int base = 0; base < cmax; base += 32) {
            int cA[4], cB[4];
            #pragma unroll
            for (int k = 0; k < 4; ++k) { cA[k] = sA[k]; cB[k] = sB[k]; }
            int nb = base + 32;
            if (nb < cmax) {   // prefetch next batch
                #pragma unroll
                for (int k = 0; k < 4; ++k) {
                    int j = nb + es + 8 * k;
                    sA[k] = esrc[j < c0 ? beg0 + j : 0];
                    sB[k] = esrc[j < c1 ? beg1 + j : 0];
                }
            }
            // validity masks (1/0)
            float mA[4], mB[4];
            #pragma unroll
            for (int k = 0; k < 4; ++k) {
                int e = base + es + 8 * k;
                mA[k] = (e < c0) ? 1.f : 0.f;
                mB[k] = (e < c1) ? 1.f : 0.f;
            }
            // 8 independent h' row-slice gathers (16B each)
            uint4 pA[4], pB[4];
            #pragma unroll
            for (int k = 0; k < 4; ++k) {
                pA[k] = *(const uint4*)&h1[(size_t)cA[k] * NH + 8 * fl];
                pB[k] = *(const uint4*)&h1[(size_t)cB[k] * NH + 8 * fl];
            }
            #pragma unroll
            for (int k = 0; k < 4; ++k) {
                const __half2* qA = (const __half2*)&pA[k];
                const __half2* qB = (const __half2*)&pB[k];
                #pragma unroll
                for (int q = 0; q < 4; ++q) {
                    float2 fA = __half22float2(qA[q]);
                    float2 fB = __half22float2(qB[q]);
                    a0v[q] += mA[k] * (f32x2){fA.x, fA.y};
                    a1v[q] += mB[k] * (f32x2){fB.x, fB.y};
                }
            }
        }
        // unpack, reduce across the 8 edge-slots (xor 8,16,32)
        float a0[8], a1[8];
        #pragma unroll
        for (int q = 0; q < 4; ++q) {
            a0[2 * q] = a0v[q][0]; a0[2 * q + 1] = a0v[q][1];
            a1[2 * q] = a1v[q][0]; a1[2 * q + 1] = a1v[q][1];
        }
        #pragma unroll
        for (int m = 8; m < 64; m <<= 1) {
            #pragma unroll
            for (int k = 0; k < 8; ++k) {
                a0[k] += __shfl_xor(a0[k], m);
                a1[k] += __shfl_xor(a1[k], m);
            }
        }
        // a = dv*S + b1, relu, fused GEMM2 partials
        float p00 = 0.f, p01 = 0.f, p10 = 0.f, p11 = 0.f;
        #pragma unroll
        for (int k = 0; k < 8; ++k) {
            float h0 = fmaxf(fmaf(dv0, a0[k], b1r[k]), 0.f);
            float h1v = fmaxf(fmaf(dv1, a1[k], b1r[k]), 0.f);
            p00 = fmaf(h0, w2[k].x, p00);
            p01 = fmaf(h0, w2[k].y, p01);
            p10 = fmaf(h1v, w2[k].x, p10);
            p11 = fmaf(h1v, w2[k].y, p11);
        }
        #pragma unroll
        for (int m = 1; m < 8; m <<= 1) {   // reduce over fl (xor 1,2,4)
            p00 += __shfl_xor(p00, m);
            p01 += __shfl_xor(p01, m);
            p10 += __shfl_xor(p10, m);
            p11 += __shfl_xor(p11, m);
        }
        if (fl == 0) {   // store g' = dv * gout
            g[(size_t)v0 * 8 + es] = __floats2half2_rn(dv0 * p00, dv0 * p01);
            if (val1) g[(size_t)v1 * 8 + es] = __floats2half2_rn(dv1 * p10, dv1 * p11);
        }
    }
}

// ---------------- agg2 + bias + log_softmax: 8-lane group/node, weightless -----
// g' table fp16 (3.2 MB, L2-resident). out_pre = dv*(g'[v] + sum g'[s]) + b2.
// 16-edge two-phase batches of masked adds; lane cl owns class pair (2cl,2cl+1).
__global__ __launch_bounds__(256) void k_agg2v(const __half2* __restrict__ g,
                                               const float* __restrict__ dinv,
                                               const int2* __restrict__ rowcnt,
                                               const int* __restrict__ esrc,
                                               const float* __restrict__ b2,
                                               float* __restrict__ out, int n) {
    int v = blockIdx.x * 32 + (threadIdx.x >> 3);
    int cl = threadIdx.x & 7;
    if (v >= n) return;
    float dv = dinv[v];
    int2 rc = rowcnt[v];
    f32x2 av;
    {   // self term g'[v], weight 1
        float2 f = __half22float2(g[(size_t)v * 8 + cl]);
        av = (f32x2){f.x, f.y};
    }
    int beg = rc.x, cnt = rc.y;
    for (int base = 0; base < cnt; base += 16) {
        int e[16];
        #pragma unroll
        for (int u = 0; u < 16; ++u) {
            int ei = base + u;
            e[u] = esrc[ei < cnt ? beg + ei : 0];
        }
        #pragma unroll
        for (int u = 0; u < 16; ++u) {
            float m = (base + u < cnt) ? 1.f : 0.f;
            float2 f = __half22float2(g[(size_t)e[u] * 8 + cl]);
            av += m * (f32x2){f.x, f.y};
        }
    }
    float ax = fmaf(dv, av[0], b2[2 * cl]);
    float ay = fmaf(dv, av[1], b2[2 * cl + 1]);
    float m = fmaxf(ax, ay);
    #pragma unroll
    for (int mask = 1; mask < 8; mask <<= 1) m = fmaxf(m, __shfl_xor(m, mask, 8));
    float ex = __expf(ax - m) + __expf(ay - m);
    #pragma unroll
    for (int mask = 1; mask < 8; mask <<= 1) ex += __shfl_xor(ex, mask, 8);
    float ls = m + __logf(ex);
    *(float2*)&out[(size_t)v * NC + 2 * cl] = make_float2(ax - ls, ay - ls);
}

extern "C" void kernel_launch(void* const* d_in, const int* in_sizes, int n_in,
                              void* d_out, int out_size, void* d_ws, size_t ws_size,
                              hipStream_t stream) {
    const float* x  = (const float*)d_in[0];
    const int*   ei = (const int*)d_in[1];
    const float* W1 = (const float*)d_in[2];
    const float* b1 = (const float*)d_in[3];
    const float* W2 = (const float*)d_in[4];
    const float* b2 = (const float*)d_in[5];
    float* out = (float*)d_out;

    const int N = in_sizes[0] / NF;
    const int E = in_sizes[1] / 2;
    const int* src = ei;
    const int* dst = ei + E;

    const int NB  = (N + 255) >> 8;                       // buckets of 256 nodes
    const int per = (E + NB - 1) / NB;
    const int cap = (per + (per >> 2) + 511) & ~511;      // +25% slack, 512-aligned

    // workspace layout (64B-aligned slices; no aliasing)
    char* ws = (char*)d_ws;
    size_t o = 0;
    auto alloc = [&](size_t bytes) {
        o = (o + 63) & ~(size_t)63;
        void* p = ws + o;
        o += bytes;
        return p;
    };
    int2*   rowcnt = (int2*)alloc((size_t)N * 8);
    float*  dinv   = (float*)alloc((size_t)N * 4);
    int*    bcur   = (int*)alloc((size_t)NBMAX * 4);
    int*    esrc   = (int*)alloc((size_t)E * 4);            // 6.4 MB
    __half* h1     = (__half*)alloc((size_t)N * NH * 2);    // 12.8 MB fp16 (pre-scaled)
    __half2* g     = (__half2*)alloc((size_t)N * NC * 2);   // 3.2 MB fp16 (g' = dv*gout)
    int*    binned = (int*)alloc((size_t)NB * cap * 4);     // ~8 MB

    int nbin = (E + BTILE - 1) / BTILE;
    int nGemm = (N + 63) / 64;

    k_binit<<<(NB + 255) / 256, 256, 0, stream>>>(bcur, NB, cap);
    k_bingemm1<<<nbin + nGemm, 256, 0, stream>>>(x, W1, h1, N, src, dst, bcur, binned,
                                                 E, NB, nbin);
    k_prep<<<NB, 256, 0, stream>>>(binned, bcur, rowcnt, dinv, esrc, h1, cap, N, NB);
    k_agg1f<<<2048, 256, 0, stream>>>(h1, dinv, rowcnt, esrc, b1, W2, g, N);
    k_agg2v<<<(N + 31) / 32, 256, 0, stream>>>(g, dinv, rowcnt, esrc, b2, out, N);
}